// Round 5
// baseline (84.040 us; speedup 1.0000x reference)
//
#include <hip/hip_runtime.h>

#define IMG_H 1080
#define IMG_W 1920
#define CH 3
#define TH 12            // rows per strip; 1080 = 90 * 12

__global__ __launch_bounds__(128, 4)
void dssim_l1_kernel(const float* __restrict__ pred,
                     const float* __restrict__ gt,
                     float* __restrict__ out) {
    constexpr float K1 = 81.0f * 0.0001f;        // 81*C1
    constexpr float K2 = 81.0f * 0.0009f;        // 81*C2
    constexpr float A3 = 0.85f / 3.0f;
    constexpr float B3 = 0.15f / 3.0f;

    const int tx    = threadIdx.x;                        // 0..63
    const int col   = blockIdx.x * 64 + tx;
    const int strip = blockIdx.y * 2 + threadIdx.y;       // 0..89
    const int h0    = strip * TH;
    const int b     = blockIdx.z;

    // reflect-clamped neighbor columns (32-bit offsets; plane < 2^31)
    const unsigned ucol = (unsigned)col;
    const unsigned cm1  = (unsigned)abs(col - 1);                       // 0 -> 1
    const unsigned cp1  = (unsigned)min(col + 1, 2 * (IMG_W - 1) - col - 1); // 1919 -> 1918

    const size_t img = (size_t)IMG_H * IMG_W;
    const float* __restrict__ xp[CH] = {
        pred + (size_t)b * CH * img,
        pred + (size_t)b * CH * img + img,
        pred + (size_t)b * CH * img + 2 * img };
    const float* __restrict__ yp[CH] = {
        gt + (size_t)b * CH * img,
        gt + (size_t)b * CH * img + img,
        gt + (size_t)b * CH * img + 2 * img };

    // rolling 3-row window stats per channel (static indices only)
    float hx[CH][3], hy[CH][3], hxx[CH][3], hyy[CH][3], hxy[CH][3];
    // 3 raw-row buffers: [c][0..2]=x(cm1,col,cp1), [3..5]=y(...)
    float pA[CH][6], pB[CH][6], pC[CH][6];

    // issue 18 loads of global row gr into buffer P; pin them before later code
#define ISSUE(P, gr)                                                        \
    {                                                                       \
        const unsigned ro_ = (unsigned)(gr) * IMG_W;                        \
        const unsigned o0_ = ro_ + cm1;                                     \
        const unsigned o1_ = ro_ + ucol;                                    \
        const unsigned o2_ = ro_ + cp1;                                     \
        _Pragma("unroll")                                                   \
        for (int c = 0; c < CH; ++c) {                                      \
            P[c][0] = xp[c][o0_];                                           \
            P[c][1] = xp[c][o1_];                                           \
            P[c][2] = xp[c][o2_];                                           \
            P[c][3] = yp[c][o0_];                                           \
            P[c][4] = yp[c][o1_];                                           \
            P[c][5] = yp[c][o2_];                                           \
        }                                                                   \
        __builtin_amdgcn_sched_barrier(0);                                  \
    }

    // turn raw buffer P into horizontal 3-tap stats in slot S
#define CONSUME(P, S)                                                       \
    {                                                                       \
        _Pragma("unroll")                                                   \
        for (int c = 0; c < CH; ++c) {                                      \
            float x0 = P[c][0], x1 = P[c][1], x2 = P[c][2];                 \
            float y0 = P[c][3], y1 = P[c][4], y2 = P[c][5];                 \
            hx[c][S]  = x0 + x1 + x2;                                       \
            hy[c][S]  = y0 + y1 + y2;                                       \
            hxx[c][S] = x0 * x0 + x1 * x1 + x2 * x2;                        \
            hyy[c][S] = y0 * y0 + y1 * y1 + y2 * y2;                        \
            hxy[c][S] = x0 * y0 + x1 * y1 + x2 * y2;                        \
        }                                                                   \
    }

    // ---- warmup: stage rows h0-1, h0 (consumed) and h0+1, h0+2 (in flight) ----
    {
        const int gm = (h0 == 0) ? 1 : h0 - 1;   // reflect(-1) = 1
        ISSUE(pA, gm);
        CONSUME(pA, 0);
        ISSUE(pB, h0);
        CONSUME(pB, 1);
        ISSUE(pC, h0 + 1);
        ISSUE(pA, h0 + 2);
    }

    float* op = out + ((size_t)b * IMG_H + h0) * IMG_W + col;

    // iter k (output row h0+k): L1 from RAWP (row k raw, loads long complete),
    // re-issue RAWP with row k+3, consume CONP (row k+1, issued 2 iters ago).
#define STEP(KK, S, RAWP, CONP, DO_ISSUE)                                   \
    {                                                                       \
        float l1s = fabsf(RAWP[0][1] - RAWP[0][4])                          \
                  + fabsf(RAWP[1][1] - RAWP[1][4])                          \
                  + fabsf(RAWP[2][1] - RAWP[2][4]);                         \
        if (DO_ISSUE) {                                                     \
            const int r_ = kb + (KK) + 3;                                   \
            const int gr_ = min(r_, 2 * (IMG_H - 1) - r_);                  \
            ISSUE(RAWP, gr_);                                               \
        }                                                                   \
        CONSUME(CONP, S);                                                   \
        float ssum = 0.0f;                                                  \
        _Pragma("unroll")                                                   \
        for (int c = 0; c < CH; ++c) {                                      \
            float ax  = hx[c][0]  + hx[c][1]  + hx[c][2];                   \
            float ay  = hy[c][0]  + hy[c][1]  + hy[c][2];                   \
            float axx = hxx[c][0] + hxx[c][1] + hxx[c][2];                  \
            float ayy = hyy[c][0] + hyy[c][1] + hyy[c][2];                  \
            float axy = hxy[c][0] + hxy[c][1] + hxy[c][2];                  \
            float u = ax * ay;                                              \
            float v = fmaf(ay, ay, ax * ax);                                \
            float w = axx + ayy;                                            \
            float num1 = fmaf(2.0f, u, K1);                                 \
            float num2 = fmaf(18.0f, axy, fmaf(-2.0f, u, K2));              \
            float den1 = v + K1;                                            \
            float den2 = fmaf(9.0f, w, K2) - v;                             \
            float s = fmaf(-0.5f, (num1 * num2) * __builtin_amdgcn_rcpf(den1 * den2), 0.5f); \
            ssum += fminf(fmaxf(s, 0.0f), 1.0f);                            \
        }                                                                   \
        *op = fmaf(A3, ssum, B3 * l1s);                                     \
        op += IMG_W;                                                        \
    }

    for (int kc = 0; kc < TH / 3 - 1; ++kc) {
        const int kb = h0 + kc * 3;
        STEP(0, 2, pB, pC, true)
        STEP(1, 0, pC, pA, true)
        STEP(2, 1, pA, pB, true)
    }
    {   // last group: skip the two issues whose rows are never consumed
        const int kb = h0 + (TH / 3 - 1) * 3;
        STEP(0, 2, pB, pC, true)
        STEP(1, 0, pC, pA, false)
        STEP(2, 1, pA, pB, false)
    }
#undef STEP
#undef CONSUME
#undef ISSUE
}

extern "C" void kernel_launch(void* const* d_in, const int* in_sizes, int n_in,
                              void* d_out, int out_size, void* d_ws, size_t ws_size,
                              hipStream_t stream) {
    const float* pred = (const float*)d_in[0];
    const float* gt   = (const float*)d_in[1];
    float* out = (float*)d_out;

    dim3 block(64, 2, 1);
    dim3 grid(IMG_W / 64, (IMG_H / TH) / 2, 4);   // 30 x 45 x 4
    dssim_l1_kernel<<<grid, block, 0, stream>>>(pred, gt, out);
}

// Round 6
// 64.432 us; speedup vs baseline: 1.3043x; 1.3043x over previous
//
#include <hip/hip_runtime.h>

#define IMG_H 1080
#define IMG_W 1920
#define CH 3

__global__ __launch_bounds__(256, 4)
void dssim_l1_kernel(const float* __restrict__ pred,
                     const float* __restrict__ gt,
                     float* __restrict__ out) {
    constexpr float K1 = 81.0f * 0.0001f;        // 81*C1
    constexpr float K2 = 81.0f * 0.0009f;        // 81*C2
    constexpr float A3 = 0.85f / 3.0f;
    constexpr float B3 = 0.15f / 3.0f;

    const int lane = threadIdx.x;                        // 0..63
    const int r    = blockIdx.y * 4 + threadIdx.y;       // output row
    const int b    = blockIdx.z;
    const int c0   = blockIdx.x * 128 + 2 * lane;        // first of 2 output cols

    const int rm = (r == 0) ? 1 : r - 1;                 // reflect
    const int rp = (r == IMG_H - 1) ? IMG_H - 2 : r + 1;

    // halo column: lane 0 needs c0-1 (reflect at image edge -> 1),
    //              lane 63 needs c0+2 (reflect 1920 -> 1918)
    const int hcol = (lane == 0) ? ((c0 == 0) ? 1 : c0 - 1)
                                 : ((c0 + 2 >= IMG_W) ? IMG_W - 2 : c0 + 2);
    const bool is_edge = (lane == 0) || (lane == 63);

    const size_t img = (size_t)IMG_H * IMG_W;
    const float* __restrict__ bx = pred + (size_t)b * CH * img;
    const float* __restrict__ by = gt   + (size_t)b * CH * img;

    // vertical accumulators: per channel, per window position (c0-1,c0,c1,c1+1)
    float vx[CH][4], vy[CH][4], vxx[CH][4], vyy[CH][4], vxy[CH][4];

#define LOADROW(R, X2, Y2, HX, HY)                                          \
    {                                                                       \
        const unsigned ro_ = (unsigned)(R) * IMG_W;                         \
        _Pragma("unroll")                                                   \
        for (int c = 0; c < CH; ++c) {                                      \
            X2[c] = *reinterpret_cast<const float2*>(bx + (size_t)c * img + ro_ + c0); \
            Y2[c] = *reinterpret_cast<const float2*>(by + (size_t)c * img + ro_ + c0); \
        }                                                                   \
        if (is_edge) {                                                      \
            _Pragma("unroll")                                               \
            for (int c = 0; c < CH; ++c) {                                  \
                HX[c] = bx[(size_t)c * img + ro_ + hcol];                   \
                HY[c] = by[(size_t)c * img + ro_ + hcol];                   \
            }                                                               \
        }                                                                   \
    }

#define CONSUME(X2, Y2, HX, HY, FIRST)                                      \
    {                                                                       \
        _Pragma("unroll")                                                   \
        for (int c = 0; c < CH; ++c) {                                      \
            float xm = __shfl_up(X2[c].y, 1);                               \
            float xp = __shfl_down(X2[c].x, 1);                             \
            float ym = __shfl_up(Y2[c].y, 1);                               \
            float yp = __shfl_down(Y2[c].x, 1);                             \
            if (lane == 0)  { xm = HX[c]; ym = HY[c]; }                     \
            if (lane == 63) { xp = HX[c]; yp = HY[c]; }                     \
            const float wx[4] = { xm, X2[c].x, X2[c].y, xp };               \
            const float wy[4] = { ym, Y2[c].x, Y2[c].y, yp };               \
            _Pragma("unroll")                                               \
            for (int k = 0; k < 4; ++k) {                                   \
                if (FIRST) {                                                \
                    vx[c][k]  = wx[k];                                      \
                    vy[c][k]  = wy[k];                                      \
                    vxx[c][k] = wx[k] * wx[k];                              \
                    vyy[c][k] = wy[k] * wy[k];                              \
                    vxy[c][k] = wx[k] * wy[k];                              \
                } else {                                                    \
                    vx[c][k] += wx[k];                                      \
                    vy[c][k] += wy[k];                                      \
                    vxx[c][k] = fmaf(wx[k], wx[k], vxx[c][k]);              \
                    vyy[c][k] = fmaf(wy[k], wy[k], vyy[c][k]);              \
                    vxy[c][k] = fmaf(wx[k], wy[k], vxy[c][k]);              \
                }                                                           \
            }                                                               \
        }                                                                   \
    }

    float2 xA[CH], yA[CH], xB[CH], yB[CH];
    float hxA[CH], hyA[CH], hxB[CH], hyB[CH];

    LOADROW(rm, xA, yA, hxA, hyA);          // row r-1 in flight
    LOADROW(r,  xB, yB, hxB, hyB);          // row r   in flight
    CONSUME(xA, yA, hxA, hyA, true);        // waits only on first batch
    LOADROW(rp, xA, yA, hxA, hyA);          // row r+1 in flight (reuse bufs)

    // L1 term from row r center values
    float l10 = 0.f, l11 = 0.f;
#pragma unroll
    for (int c = 0; c < CH; ++c) {
        l10 += fabsf(xB[c].x - yB[c].x);
        l11 += fabsf(xB[c].y - yB[c].y);
    }

    CONSUME(xB, yB, hxB, hyB, false);       // row r
    CONSUME(xA, yA, hxA, hyA, false);       // row r+1

    // epilogue: horizontal 3-sums + SSIM per output column
    float res0 = B3 * l10;
    float res1 = B3 * l11;
#pragma unroll
    for (int c = 0; c < CH; ++c) {
        const float tx  = vx[c][1]  + vx[c][2];
        const float ty  = vy[c][1]  + vy[c][2];
        const float txx = vxx[c][1] + vxx[c][2];
        const float tyy = vyy[c][1] + vyy[c][2];
        const float txy = vxy[c][1] + vxy[c][2];
#pragma unroll
        for (int j = 0; j < 2; ++j) {
            const int e = (j == 0) ? 0 : 3;
            const float ax  = tx  + vx[c][e];
            const float ay  = ty  + vy[c][e];
            const float axx = txx + vxx[c][e];
            const float ayy = tyy + vyy[c][e];
            const float axy = txy + vxy[c][e];

            // SSIM scaled by 81 (cancels in n/d): see R3 derivation
            const float u = ax * ay;
            const float v = fmaf(ay, ay, ax * ax);
            const float w = axx + ayy;
            const float num1 = fmaf(2.0f, u, K1);
            const float num2 = fmaf(18.0f, axy, fmaf(-2.0f, u, K2));
            const float den1 = v + K1;
            const float den2 = fmaf(9.0f, w, K2) - v;
            float s = fmaf(-0.5f, (num1 * num2) * __builtin_amdgcn_rcpf(den1 * den2), 0.5f);
            s = fminf(fmaxf(s, 0.0f), 1.0f);
            if (j == 0) res0 = fmaf(A3, s, res0);
            else        res1 = fmaf(A3, s, res1);
        }
    }

    float2 o; o.x = res0; o.y = res1;
    *reinterpret_cast<float2*>(out + ((size_t)b * IMG_H + r) * IMG_W + c0) = o;

#undef CONSUME
#undef LOADROW
}

extern "C" void kernel_launch(void* const* d_in, const int* in_sizes, int n_in,
                              void* d_out, int out_size, void* d_ws, size_t ws_size,
                              hipStream_t stream) {
    const float* pred = (const float*)d_in[0];
    const float* gt   = (const float*)d_in[1];
    float* out = (float*)d_out;

    dim3 block(64, 4, 1);
    dim3 grid(IMG_W / 128, IMG_H / 4, 4);   // 15 x 270 x 4
    dssim_l1_kernel<<<grid, block, 0, stream>>>(pred, gt, out);
}